// Round 1
// baseline (2339.695 us; speedup 1.0000x reference)
//
#include <hip/hip_runtime.h>
#include <math.h>

#define HD 128
#define NBR 8
#define LSTEPS 64
#define TILE_B 32
#define HT_PAD 36     // hT row stride (floats): 36*4=144B -> float4-aligned rows; GEMM reads are wave-uniform broadcasts
#define PART_PAD 133  // 133%32=5, 5*lb mod 32 spreads 32 lanes over 32 banks -> conflict-free scalar access

// workspace layout (floats)
#define WPT_OFF   0        // w_hh permuted-transposed: [k][4*hh+q] = w_hh[q*128+hh][k]   (128*512)
#define WIPT_OFF  65536    // w_ih same layout                                            (128*512)
#define PP_OFF    131072   // P' = w_emb@w_ih^T + (b_ih+b_hh), layout [j][q*128+hh]       (8*512)
#define BSUM_OFF  135168   // (b_ih+b_hh) permuted [q*128+hh]                             (512)
// total ws: 135680 floats = 542720 bytes

__global__ __launch_bounds__(256) void setup_kernel(
    const float* __restrict__ w_emb, const float* __restrict__ w_ih,
    const float* __restrict__ w_hh, const float* __restrict__ b_ih,
    const float* __restrict__ b_hh, float* __restrict__ ws)
{
  int tid = blockIdx.x * blockDim.x + threadIdx.x;
  if (tid < 65536) {
    int k = tid >> 9, col = tid & 511;
    int hh = col >> 2, q = col & 3;
    ws[WPT_OFF + tid]  = w_hh[(q*HD + hh)*HD + k];
    ws[WIPT_OFF + tid] = w_ih[(q*HD + hh)*HD + k];
  }
  if (tid < 4096) {
    int j = tid >> 9, rem = tid & 511;
    int q = rem >> 7, hh2 = rem & 127;
    const float* wr = w_ih + (q*HD + hh2)*HD;
    const float* er = w_emb + j*HD;
    float s = 0.f;
    for (int k = 0; k < HD; ++k) s = fmaf(er[k], wr[k], s);
    // bias folded: gate(t>0) = 0.5*(P' + q0') + acc, with P' = P + bsum, q0' = q0 + bsum
    ws[PP_OFF + (size_t)j*512 + q*HD + hh2] = s + b_ih[q*HD + hh2] + b_hh[q*HD + hh2];
  }
  if (tid < 512) {
    int q = tid >> 7, hh2 = tid & 127;
    ws[BSUM_OFF + tid] = b_ih[q*HD + hh2] + b_hh[q*HD + hh2];
  }
}

// 512 threads, TILE_B=32: thread (hh = tid&127, bg = tid>>7) owns 8 batches (bg*8..bg*8+7).
// __launch_bounds__(512,4): 4 waves/EU min -> VGPR capped at 128 -> 2 blocks/CU co-resident.
__global__ __launch_bounds__(512, 4) void ctrl_kernel(
    const int* __restrict__ class_ids,
    const float* __restrict__ gumbel_u,
    const float* __restrict__ g_emb,
    const float* __restrict__ w_soft,
    const float* __restrict__ ws,
    float* __restrict__ out,
    int Btot)
{
  __shared__ float hT[HD * HT_PAD];            // 18432 B: h transposed [k][b]
  __shared__ float wsoft_l[NBR * HD];          // 4096 B
  __shared__ float part_l[TILE_B * PART_PAD];  // 17024 B
  __shared__ float pp_l[NBR * 512];            // 16384 B: P' staged in LDS
  __shared__ int   br_l[TILE_B];               // 128 B   (total ~55 KB -> 2 blocks/CU fit 160 KB)

  const int tid = threadIdx.x;
  const int b0  = blockIdx.x * TILE_B;
  const size_t BL = (size_t)Btot * LSTEPS;

  const float* __restrict__ wpT  = ws + WPT_OFF;
  const float* __restrict__ wipT = ws + WIPT_OFF;

  for (int i = tid; i < NBR*HD; i += 512) wsoft_l[i] = w_soft[i];
  for (int i = tid; i < NBR*512; i += 512) pp_l[i] = ws[PP_OFF + i];

  const int hh = tid & 127;   // hidden index
  const int bg = tid >> 7;    // batch group 0..3 (8 batches each)

  // ---- stage x0^T = g_emb[class_ids]^T into hT ----
  {
    int sb = tid >> 4;        // 0..31 batch
    int kc = tid & 15;        // k-chunk of 8
    int cid = class_ids[b0 + sb];
    const float* src = g_emb + (size_t)cid * HD + kc*8;
    float4 v0 = *(const float4*)(src);
    float4 v1 = *(const float4*)(src + 4);
    int kb = kc*8;
    hT[(kb+0)*HT_PAD + sb] = v0.x;
    hT[(kb+1)*HT_PAD + sb] = v0.y;
    hT[(kb+2)*HT_PAD + sb] = v0.z;
    hT[(kb+3)*HT_PAD + sb] = v0.w;
    hT[(kb+4)*HT_PAD + sb] = v1.x;
    hT[(kb+5)*HT_PAD + sb] = v1.y;
    hT[(kb+6)*HT_PAD + sb] = v1.z;
    hT[(kb+7)*HT_PAD + sb] = v1.w;
  }
  __syncthreads();

  // ---- q0' = x0 @ w_ih^T + (b_ih+b_hh), kept in registers for all 64 steps ----
  float q0[4][8];
  #pragma unroll
  for (int q = 0; q < 4; ++q)
    #pragma unroll
    for (int j = 0; j < 8; ++j) q0[q][j] = 0.f;

  {
    const float* wp = wipT + 4*hh;
    const float* hr = &hT[bg*8];
    #pragma unroll 2
    for (int k = 0; k < HD; ++k) {
      float4 w  = *(const float4*)(wp);
      float4 ha = *(const float4*)(hr);
      float4 hb = *(const float4*)(hr + 4);
      wp += 512; hr += HT_PAD;
      float hv[8] = {ha.x,ha.y,ha.z,ha.w,hb.x,hb.y,hb.z,hb.w};
      float wv[4] = {w.x,w.y,w.z,w.w};
      #pragma unroll
      for (int q = 0; q < 4; ++q)
        #pragma unroll
        for (int j = 0; j < 8; ++j)
          q0[q][j] = fmaf(hv[j], wv[q], q0[q][j]);
    }
  }
  #pragma unroll
  for (int q = 0; q < 4; ++q) {
    float bs = ws[BSUM_OFF + q*HD + hh];
    #pragma unroll
    for (int j = 0; j < 8; ++j) q0[q][j] += bs;
  }
  __syncthreads();

  float c[8];
  #pragma unroll
  for (int j = 0; j < 8; ++j) c[j] = 0.f;

  for (int t = 0; t < LSTEPS; ++t) {
    // prefetch gumbel u for this step (overlaps GEMM)
    float4 ua = make_float4(0,0,0,0), ub = make_float4(0,0,0,0);
    if (tid < TILE_B) {
      const float* up = gumbel_u + ((size_t)t * Btot + (b0 + tid)) * NBR;
      ua = *(const float4*)up;
      ub = *(const float4*)(up + 4);
    }

    // ---- GEMM: acc = h @ w_hh^T (skipped at t=0 since h0 = 0) ----
    float acc[4][8];
    #pragma unroll
    for (int q = 0; q < 4; ++q)
      #pragma unroll
      for (int j = 0; j < 8; ++j) acc[q][j] = 0.f;

    if (t > 0) {
      const float* wp = wpT + 4*hh;
      const float* hr = &hT[bg*8];
      #pragma unroll 2
      for (int k = 0; k < HD; ++k) {
        float4 w  = *(const float4*)(wp);
        float4 ha = *(const float4*)(hr);
        float4 hb = *(const float4*)(hr + 4);
        wp += 512; hr += HT_PAD;
        float hv[8] = {ha.x,ha.y,ha.z,ha.w,hb.x,hb.y,hb.z,hb.w};
        float wv[4] = {w.x,w.y,w.z,w.w};
        #pragma unroll
        for (int q = 0; q < 4; ++q)
          #pragma unroll
          for (int j = 0; j < 8; ++j)
            acc[q][j] = fmaf(hv[j], wv[q], acc[q][j]);
      }
    }

    // ---- combine x-part, LSTM pointwise (registers only) ----
    float h2v[8];
    #pragma unroll
    for (int j = 0; j < 8; ++j) {
      float g4[4];
      if (t == 0) {
        #pragma unroll
        for (int q = 0; q < 4; ++q) g4[q] = q0[q][j];   // acc==0, bias already in q0'
      } else {
        int br = br_l[bg*8 + j];
        const float* pr = pp_l + br*512 + hh;
        #pragma unroll
        for (int q = 0; q < 4; ++q)
          g4[q] = fmaf(0.5f, pr[q*HD] + q0[q][j], acc[q][j]);
      }
      float iv = 1.f/(1.f + expf(-g4[0]));
      float fv = 1.f/(1.f + expf(-g4[1]));
      float gv = tanhf(g4[2]);
      float ov = 1.f/(1.f + expf(-g4[3]));
      float c2 = fv*c[j] + iv*gv;
      c[j] = c2;
      h2v[j] = ov * tanhf(c2);
    }
    __syncthreads();   // (A) all hT reads of this step done before overwrite

    {
      float* dst = &hT[hh*HT_PAD + bg*8];
      *(float4*)(dst)   = make_float4(h2v[0],h2v[1],h2v[2],h2v[3]);
      *(float4*)(dst+4) = make_float4(h2v[4],h2v[5],h2v[6],h2v[7]);
    }
    __syncthreads();   // (B) new h visible

    // ---- logit partials: thread (lb = tid&31, ch = tid>>5), 8-k chunk each ----
    {
      int lb = tid & 31, ch = tid >> 5;
      float part[8];
      #pragma unroll
      for (int nb = 0; nb < 8; ++nb) part[nb] = 0.f;
      #pragma unroll
      for (int i = 0; i < 8; ++i) {
        float hvv = hT[(ch*8 + i)*HT_PAD + lb];
        #pragma unroll
        for (int nb = 0; nb < 8; ++nb)
          part[nb] = fmaf(hvv, wsoft_l[nb*HD + ch*8 + i], part[nb]);
      }
      #pragma unroll
      for (int nb = 0; nb < 8; ++nb)
        part_l[lb*PART_PAD + nb*16 + ch] = part[nb];
    }
    __syncthreads();   // (C)

    // ---- sampling: one thread per batch row (other co-resident block's GEMM overlaps this) ----
    if (tid < TILE_B) {
      int lb = tid;
      float lg[8];
      #pragma unroll
      for (int nb = 0; nb < 8; ++nb) {
        float s = 0.f;
        #pragma unroll
        for (int ch = 0; ch < 16; ++ch) s += part_l[lb*PART_PAD + nb*16 + ch];
        lg[nb] = 2.5f * tanhf(s / 5.0f);
      }
      float uv[8] = {ua.x,ua.y,ua.z,ua.w,ub.x,ub.y,ub.z,ub.w};
      int br = 0; float best;
      {
        float uc = fminf(fmaxf(uv[0], 1e-8f), 0.99999999f);
        best = lg[0] - logf(-logf(uc));
      }
      #pragma unroll
      for (int nb = 1; nb < 8; ++nb) {
        float uc = fminf(fmaxf(uv[nb], 1e-8f), 0.99999999f);
        float y = lg[nb] - logf(-logf(uc));
        if (y > best) { best = y; br = nb; }   // strict >  == first-occurrence argmax
      }
      float m = lg[0];
      #pragma unroll
      for (int nb = 1; nb < 8; ++nb) m = fmaxf(m, lg[nb]);
      float se = 0.f;
      #pragma unroll
      for (int nb = 0; nb < 8; ++nb) se += expf(lg[nb] - m);
      float lse = logf(se);
      float lp = (lg[br] - m) - lse;
      float ent = 0.f;
      #pragma unroll
      for (int nb = 0; nb < 8; ++nb) {
        float lpi = (lg[nb] - m) - lse;
        ent -= expf(lpi) * lpi;
      }
      size_t row = (size_t)(b0 + lb) * LSTEPS + t;
      out[row]        = (float)br;
      out[BL + row]   = lp;
      out[2*BL + row] = ent;
      out[3*BL + row] = expf(lp);
      br_l[lb] = br;
    }
    __syncthreads();   // (E) br_l visible for next step's combine
  }
}

extern "C" void kernel_launch(void* const* d_in, const int* in_sizes, int n_in,
                              void* d_out, int out_size, void* d_ws, size_t ws_size,
                              hipStream_t stream) {
  const int*   class_ids = (const int*)d_in[0];
  const float* gumbel_u  = (const float*)d_in[1];
  const float* g_emb     = (const float*)d_in[2];
  const float* w_emb     = (const float*)d_in[3];
  const float* w_soft    = (const float*)d_in[4];
  const float* w_ih      = (const float*)d_in[5];
  const float* w_hh      = (const float*)d_in[6];
  const float* b_ih      = (const float*)d_in[7];
  const float* b_hh      = (const float*)d_in[8];
  float* out = (float*)d_out;
  float* ws  = (float*)d_ws;
  int B = in_sizes[0];

  hipLaunchKernelGGL(setup_kernel, dim3(256), dim3(256), 0, stream,
                     w_emb, w_ih, w_hh, b_ih, b_hh, ws);
  hipLaunchKernelGGL(ctrl_kernel, dim3(B / TILE_B), dim3(512), 0, stream,
                     class_ids, gumbel_u, g_emb, w_soft, ws, out, B);
}

// Round 2
// 2080.046 us; speedup vs baseline: 1.1248x; 1.1248x over previous
//
#include <hip/hip_runtime.h>
#include <math.h>

#define HD 128
#define NBR 8
#define LSTEPS 64
#define TILE_B 32
#define HT_PAD 36     // 144B rows: float4-aligned; stride%32==4 -> perfect b128 write distribution
#define PART_PAD 132  // multiple of 4 -> float4-aligned rows; conflicts 2-4 way (cheap)

// workspace layout (floats)
#define WPT_OFF   0        // w_hh permuted-transposed: [k][4*hh+q] = w_hh[q*128+hh][k]   (128*512)
#define WIPT_OFF  65536    // w_ih same layout                                            (128*512)
#define PP_OFF    131072   // P'' = w_emb@w_ih^T + bsum, layout [j][4*hh+q]               (8*512)
#define BSUM_OFF  135168   // (b_ih+b_hh) permuted [q*128+hh]                             (512)
// total ws: 135680 floats = 542720 bytes

__global__ __launch_bounds__(256) void setup_kernel(
    const float* __restrict__ w_emb, const float* __restrict__ w_ih,
    const float* __restrict__ w_hh, const float* __restrict__ b_ih,
    const float* __restrict__ b_hh, float* __restrict__ ws)
{
  int tid = blockIdx.x * blockDim.x + threadIdx.x;
  if (tid < 65536) {
    int k = tid >> 9, col = tid & 511;
    int hh = col >> 2, q = col & 3;
    ws[WPT_OFF + tid]  = w_hh[(q*HD + hh)*HD + k];
    ws[WIPT_OFF + tid] = w_ih[(q*HD + hh)*HD + k];
  }
  if (tid < 4096) {
    int j = tid >> 9, rem = tid & 511;
    int q = rem >> 7, hh2 = rem & 127;
    const float* wr = w_ih + (q*HD + hh2)*HD;
    const float* er = w_emb + j*HD;
    float s = 0.f;
    for (int k = 0; k < HD; ++k) s = fmaf(er[k], wr[k], s);
    // layout [j][4*hh+q] so the combine phase reads one float4 per (j, hh)
    ws[PP_OFF + (size_t)j*512 + 4*hh2 + q] = s + b_ih[q*HD + hh2] + b_hh[q*HD + hh2];
  }
  if (tid < 512) {
    int q = tid >> 7, hh2 = tid & 127;
    ws[BSUM_OFF + tid] = b_ih[q*HD + hh2] + b_hh[q*HD + hh2];
  }
}

// fast transcendentals (hw exp2/log2-based; ~1e-7 rel err, same class as fp32 reordering)
__device__ __forceinline__ float fsig(float x) {
  return __fdividef(1.f, 1.f + __expf(-x));
}
__device__ __forceinline__ float ftanh(float x) {
  float ax = fabsf(x);
  float e  = __expf(-2.f * ax);
  float r  = __fdividef(1.f - e, 1.f + e);
  return copysignf(r, x);
}

// one GEMM k-step: 32 explicit-component FMAs (no arrays -> no unpack movs)
#define ROWQ(qi, wq) \
  acc[qi][0] = fmaf(ha.x, wq, acc[qi][0]); acc[qi][1] = fmaf(ha.y, wq, acc[qi][1]); \
  acc[qi][2] = fmaf(ha.z, wq, acc[qi][2]); acc[qi][3] = fmaf(ha.w, wq, acc[qi][3]); \
  acc[qi][4] = fmaf(hb.x, wq, acc[qi][4]); acc[qi][5] = fmaf(hb.y, wq, acc[qi][5]); \
  acc[qi][6] = fmaf(hb.z, wq, acc[qi][6]); acc[qi][7] = fmaf(hb.w, wq, acc[qi][7]);

#define KSTEP(WPTR, HPTR) do { \
    float4 w  = *(const float4*)(WPTR); \
    float4 ha = *(const float4*)(HPTR); \
    float4 hb = *(const float4*)((HPTR) + 4); \
    ROWQ(0, w.x) ROWQ(1, w.y) ROWQ(2, w.z) ROWQ(3, w.w) \
  } while (0)

__global__ __launch_bounds__(512, 4) void ctrl_kernel(
    const int* __restrict__ class_ids,
    const float* __restrict__ gumbel_u,
    const float* __restrict__ g_emb,
    const float* __restrict__ w_soft,
    const float* __restrict__ ws,
    float* __restrict__ out,
    int Btot)
{
  __shared__ __align__(16) float hT0[HD * HT_PAD];       // 18432 B
  __shared__ __align__(16) float hT1[HD * HT_PAD];       // 18432 B (double buffer: kills barrier A)
  __shared__ __align__(16) float wsoft_l[NBR * HD];      // 4096 B
  __shared__ __align__(16) float part_l[TILE_B * PART_PAD]; // 16896 B
  __shared__ __align__(16) float pp_l[NBR * 512];        // 16384 B
  __shared__ int br_l[TILE_B];                           // 128 B  (total ~74.4 KB -> 2 blocks/CU)

  const int tid = threadIdx.x;
  const int b0  = blockIdx.x * TILE_B;
  const size_t BL = (size_t)Btot * LSTEPS;

  const float* __restrict__ wpT  = ws + WPT_OFF;
  const float* __restrict__ wipT = ws + WIPT_OFF;

  for (int i = tid; i < NBR*HD; i += 512) wsoft_l[i] = w_soft[i];
  for (int i = tid; i < NBR*512; i += 512) pp_l[i] = ws[PP_OFF + i];

  const int hh = tid & 127;   // hidden index
  const int bg = tid >> 7;    // batch group 0..3 (8 batches each)

  // ---- stage x0^T = g_emb[class_ids]^T into hT0 ----
  {
    int sb = tid >> 4;        // 0..31 batch
    int kc = tid & 15;        // k-chunk of 8
    int cid = class_ids[b0 + sb];
    const float* src = g_emb + (size_t)cid * HD + kc*8;
    float4 v0 = *(const float4*)(src);
    float4 v1 = *(const float4*)(src + 4);
    int kb = kc*8;
    hT0[(kb+0)*HT_PAD + sb] = v0.x;
    hT0[(kb+1)*HT_PAD + sb] = v0.y;
    hT0[(kb+2)*HT_PAD + sb] = v0.z;
    hT0[(kb+3)*HT_PAD + sb] = v0.w;
    hT0[(kb+4)*HT_PAD + sb] = v1.x;
    hT0[(kb+5)*HT_PAD + sb] = v1.y;
    hT0[(kb+6)*HT_PAD + sb] = v1.z;
    hT0[(kb+7)*HT_PAD + sb] = v1.w;
  }
  __syncthreads();

  // ---- q0h = 0.5*(x0 @ w_ih^T + bsum), parked in 32 AGPRs for all 64 steps ----
  float qpark[32];   // forced to AGPRs by the "a" asm constraints below
  {
    float acc[4][8];
    #pragma unroll
    for (int q = 0; q < 4; ++q)
      #pragma unroll
      for (int j = 0; j < 8; ++j) acc[q][j] = 0.f;

    const float* wrow = wipT + 4*hh;
    const float* hr   = hT0 + bg*8;
    #pragma unroll 2
    for (int k = 0; k < HD; ++k) {
      KSTEP(wrow, hr);
      wrow += 512; hr += HT_PAD;
    }
    #pragma unroll
    for (int q = 0; q < 4; ++q) {
      float bs = ws[BSUM_OFF + q*HD + hh];
      #pragma unroll
      for (int j = 0; j < 8; ++j) {
        float v = 0.5f * (acc[q][j] + bs);
        asm("v_accvgpr_write_b32 %0, %1" : "=a"(qpark[q*8+j]) : "v"(v));
      }
    }
  }
  __syncthreads();

  float c[8];
  #pragma unroll
  for (int j = 0; j < 8; ++j) c[j] = 0.f;

  float* hcur = hT0;
  float* hnxt = hT1;

  for (int t = 0; t < LSTEPS; ++t) {
    // ---- prefetch gumbel u and convert to gumbel noise (overlaps GEMM) ----
    float gmb[8];
    if (tid < TILE_B) {
      const float* up = gumbel_u + ((size_t)t * Btot + (b0 + tid)) * NBR;
      float4 ua = *(const float4*)up;
      float4 ub = *(const float4*)(up + 4);
      float uv[8] = {ua.x,ua.y,ua.z,ua.w,ub.x,ub.y,ub.z,ub.w};
      #pragma unroll
      for (int nb = 0; nb < 8; ++nb) {
        float uc = fminf(fmaxf(uv[nb], 1e-8f), 0.99999999f);
        gmb[nb] = -__logf(-__logf(uc));
      }
    }

    // ---- acc starts at q0h (x0-part + bias pre-folded); GEMM adds h @ w_hh^T ----
    float acc[4][8];
    #pragma unroll
    for (int q = 0; q < 4; ++q)
      #pragma unroll
      for (int j = 0; j < 8; ++j)
        asm("v_accvgpr_read_b32 %0, %1" : "=v"(acc[q][j]) : "a"(qpark[q*8+j]));

    if (t > 0) {
      __builtin_amdgcn_s_setprio(1);
      const float* wrow = wpT + 4*hh;
      const float* hr   = hcur + bg*8;
      #pragma unroll 2
      for (int k = 0; k < HD; ++k) {
        KSTEP(wrow, hr);
        wrow += 512; hr += HT_PAD;
      }
      __builtin_amdgcn_s_setprio(0);
    }

    // ---- combine x-part, LSTM pointwise (registers only) ----
    float h2v[8];
    #pragma unroll
    for (int j = 0; j < 8; ++j) {
      float gi, gf, gg, go;
      if (t == 0) {
        gi = 2.f*acc[0][j]; gf = 2.f*acc[1][j];
        gg = 2.f*acc[2][j]; go = 2.f*acc[3][j];
      } else {
        int br = br_l[bg*8 + j];
        float4 pv = *(const float4*)(&pp_l[br*512 + 4*hh]);
        gi = fmaf(0.5f, pv.x, acc[0][j]);
        gf = fmaf(0.5f, pv.y, acc[1][j]);
        gg = fmaf(0.5f, pv.z, acc[2][j]);
        go = fmaf(0.5f, pv.w, acc[3][j]);
      }
      float iv = fsig(gi);
      float fv = fsig(gf);
      float gv = ftanh(gg);
      float ov = fsig(go);
      float c2 = fmaf(fv, c[j], iv*gv);
      c[j] = c2;
      h2v[j] = ov * ftanh(c2);
    }

    // write h_{t+1} into the OTHER buffer: no barrier needed before the write
    {
      float* dst = &hnxt[hh*HT_PAD + bg*8];
      *(float4*)(dst)   = make_float4(h2v[0],h2v[1],h2v[2],h2v[3]);
      *(float4*)(dst+4) = make_float4(h2v[4],h2v[5],h2v[6],h2v[7]);
    }
    __syncthreads();   // (B) new h visible

    // ---- logit partials: thread (lb = tid&31, ch = tid>>5), 8-k chunk each ----
    {
      int lb = tid & 31, ch = tid >> 5;
      const float* hp = hnxt + (ch*8)*HT_PAD + lb;
      float hv[8];
      #pragma unroll
      for (int i = 0; i < 8; ++i) hv[i] = hp[i*HT_PAD];
      #pragma unroll
      for (int nb = 0; nb < 8; ++nb) {
        const float4* wr = (const float4*)&wsoft_l[nb*HD + ch*8];
        float4 wa = wr[0], wb = wr[1];
        float p = 0.f;
        p = fmaf(hv[0], wa.x, p); p = fmaf(hv[1], wa.y, p);
        p = fmaf(hv[2], wa.z, p); p = fmaf(hv[3], wa.w, p);
        p = fmaf(hv[4], wb.x, p); p = fmaf(hv[5], wb.y, p);
        p = fmaf(hv[6], wb.z, p); p = fmaf(hv[7], wb.w, p);
        part_l[lb*PART_PAD + nb*16 + ch] = p;
      }
    }
    __syncthreads();   // (C)

    // ---- sampling: one thread per batch row ----
    if (tid < TILE_B) {
      int lb = tid;
      float lg[8];
      #pragma unroll
      for (int nb = 0; nb < 8; ++nb) {
        const float4* pr = (const float4*)&part_l[lb*PART_PAD + nb*16];
        float4 pa = pr[0], pb = pr[1], pc = pr[2], pd = pr[3];
        float s = pa.x; s += pa.y; s += pa.z; s += pa.w;
        s += pb.x; s += pb.y; s += pb.z; s += pb.w;
        s += pc.x; s += pc.y; s += pc.z; s += pc.w;
        s += pd.x; s += pd.y; s += pd.z; s += pd.w;
        lg[nb] = 2.5f * ftanh(s * 0.2f);
      }
      int br = 0; float best = lg[0] + gmb[0];
      #pragma unroll
      for (int nb = 1; nb < 8; ++nb) {
        float y = lg[nb] + gmb[nb];
        if (y > best) { best = y; br = nb; }   // strict > == first-occurrence argmax
      }
      br_l[lb] = br;
      float m = lg[0];
      #pragma unroll
      for (int nb = 1; nb < 8; ++nb) m = fmaxf(m, lg[nb]);
      float se = 0.f;
      #pragma unroll
      for (int nb = 0; nb < 8; ++nb) se += __expf(lg[nb] - m);
      float lse = __logf(se);
      float lp = (lg[br] - m) - lse;
      size_t row = (size_t)(b0 + lb) * LSTEPS + t;
      out[row]        = (float)br;
      out[BL + row]   = lp;
      out[3*BL + row] = __expf(lp);
      float ent = 0.f;
      #pragma unroll
      for (int nb = 0; nb < 8; ++nb) {
        float lpi = (lg[nb] - m) - lse;
        ent -= __expf(lpi) * lpi;
      }
      out[2*BL + row] = ent;
    }
    __syncthreads();   // (E) br_l visible for next step's combine

    float* tmp = hcur; hcur = hnxt; hnxt = tmp;
  }
}

extern "C" void kernel_launch(void* const* d_in, const int* in_sizes, int n_in,
                              void* d_out, int out_size, void* d_ws, size_t ws_size,
                              hipStream_t stream) {
  const int*   class_ids = (const int*)d_in[0];
  const float* gumbel_u  = (const float*)d_in[1];
  const float* g_emb     = (const float*)d_in[2];
  const float* w_emb     = (const float*)d_in[3];
  const float* w_soft    = (const float*)d_in[4];
  const float* w_ih      = (const float*)d_in[5];
  const float* w_hh      = (const float*)d_in[6];
  const float* b_ih      = (const float*)d_in[7];
  const float* b_hh      = (const float*)d_in[8];
  float* out = (float*)d_out;
  float* ws  = (float*)d_ws;
  int B = in_sizes[0];

  hipLaunchKernelGGL(setup_kernel, dim3(256), dim3(256), 0, stream,
                     w_emb, w_ih, w_hh, b_ih, b_hh, ws);
  hipLaunchKernelGGL(ctrl_kernel, dim3(B / TILE_B), dim3(512), 0, stream,
                     class_ids, gumbel_u, g_emb, w_soft, ws, out, B);
}